// Round 4
// baseline (1792.967 us; speedup 1.0000x reference)
//
#include <hip/hip_runtime.h>

// Fused CKY inside-outside (log semiring), B=16, S=192. One workgroup per
// batch; EVERYTHING in LDS as two packed upper triangles:
//   ch = inside chart; od = softplus(rules) initially (sp table for inside),
//   overwritten in place by the outside pass (od = outside + sp).
// Rows padded to even length -> strided per-lane "column" accesses have odd
// address deltas -> <=2 lanes/bank (free). 2 * 74496 B = 148992 B LDS.
//
//   inside:  ch[i][j] = sp[i][j] + LSE_{k}( ch[i][k] + ch[k+1][j] )
//   Z[b] = ch[0][L-1]
//   outside: od[0][L-1] = sp (o=0);
//     od[i][j] = sp[i][j] + LSE( od[i][p] + ch[j+1][p]  (p=j+1..L-1),
//                                od[a][j] + ch[a][i-1]  (a=0..i-1) )
//   marginal[i][j] = sigmoid(r)*exp((od[i][j]-sp) + ch[i][j] - Z), i<=j<L

#define SS 192
#define BB 16
#define NT 1024
#define TRI_SIZE 18624   // sum of even-padded row lengths

__device__ __forceinline__ int triOff(int i) {
  // len_t = (192 - t) + (t & 1)  (pad odd-length rows to even)
  return 192 * i - ((i * (i - 1)) >> 1) + (i >> 1);
}
__device__ __forceinline__ float softplusf(float x) {
  return fmaxf(x, 0.f) + log1pf(__expf(-fabsf(x)));
}

__global__ __launch_bounds__(NT) void cky_fused(const float* __restrict__ rules,
                                                const int* __restrict__ lens,
                                                float* __restrict__ outZ,
                                                float* __restrict__ marg) {
  extern __shared__ float lds[];
  float* __restrict__ ch = lds;             // inside chart triangle
  float* __restrict__ od = lds + TRI_SIZE;  // sp -> (outside + sp) triangle
  const int b = blockIdx.x;
  const int tid = threadIdx.x;
  const float* __restrict__ R = rules + (size_t)b * SS * SS;

  // prologue: od = softplus(R) on the triangle; chart diagonal
  for (int idx = tid; idx < SS * SS; idx += NT) {
    int i = idx / SS, j = idx - i * SS;
    if (i <= j) {
      float sp = softplusf(R[idx]);
      od[triOff(i) + (j - i)] = sp;
      if (i == j) ch[triOff(i)] = sp;
    }
  }
  __syncthreads();

  // ---------------- inside ----------------
  for (int w = 1; w < SS; ++w) {
    const int ncell = SS - w;
    int Glog = 31 - __clz(NT / ncell);
    if (Glog > 6) Glog = 6;
    const int G = 1 << Glog;
    const int c = tid >> Glog;
    const int lane = tid & (G - 1);
    if (c < ncell) {
      const int i = c, j = c + w;
      const int rowI = triOff(i);
      const float sp = od[rowI + w];             // sp[i][j] (LDS)
      float m = -1e30f;
      #pragma unroll 4
      for (int k = i + lane; k < j; k += G)
        m = fmaxf(m, ch[rowI + (k - i)] + ch[triOff(k + 1) + (j - k - 1)]);
      for (int off = G >> 1; off; off >>= 1)
        m = fmaxf(m, __shfl_xor(m, off));
      float s = 0.f;
      #pragma unroll 4
      for (int k = i + lane; k < j; k += G)
        s += __expf(ch[rowI + (k - i)] + ch[triOff(k + 1) + (j - k - 1)] - m);
      for (int off = G >> 1; off; off >>= 1)
        s += __shfl_xor(s, off);
      if (lane == 0) ch[rowI + w] = sp + m + __logf(s);
    }
    __syncthreads();
  }

  const int L = lens[b];
  if (tid == 0) outZ[b] = ch[L - 1];             // triOff(0)==0 -> ch[0][L-1]

  // ---------------- outside (od updated in place; root stays = sp) ----------
  for (int w = L - 2; w >= 0; --w) {
    const int ncell = L - w;
    int Glog = 31 - __clz(NT / ncell);
    if (Glog > 6) Glog = 6;
    const int G = 1 << Glog;
    const int c = tid >> Glog;
    const int lane = tid & (G - 1);
    if (c < ncell) {
      const int i = c, j = c + w;
      const int rowI = triOff(i);
      const int rowJ1 = triOff(j + 1);
      const float sp = od[rowI + w];             // current value == sp[i][j]
      float m = -1e30f;
      #pragma unroll 4
      for (int p = j + 1 + lane; p < L; p += G)  // parent [i,p], left child
        m = fmaxf(m, od[rowI + (p - i)] + ch[rowJ1 + (p - j - 1)]);
      #pragma unroll 4
      for (int a = lane; a < i; a += G)          // parent [a,j], right child
        m = fmaxf(m, od[triOff(a) + (j - a)] + ch[triOff(a) + (i - 1 - a)]);
      for (int off = G >> 1; off; off >>= 1)
        m = fmaxf(m, __shfl_xor(m, off));
      float s = 0.f;
      #pragma unroll 4
      for (int p = j + 1 + lane; p < L; p += G)
        s += __expf(od[rowI + (p - i)] + ch[rowJ1 + (p - j - 1)] - m);
      #pragma unroll 4
      for (int a = lane; a < i; a += G)
        s += __expf(od[triOff(a) + (j - a)] + ch[triOff(a) + (i - 1 - a)] - m);
      for (int off = G >> 1; off; off >>= 1)
        s += __shfl_xor(s, off);
      if (lane == 0) od[rowI + w] = sp + m + __logf(s);
    }
    __syncthreads();
  }

  // ---------------- marginals ----------------
  const float Z = ch[L - 1];
  float* __restrict__ Mb = marg + (size_t)b * SS * SS;
  for (int idx = tid; idx < SS * SS; idx += NT) {
    int i = idx / SS, j = idx - i * SS;
    float val = 0.f;
    if (i <= j && j < L) {
      float r = R[idx];
      float sp = softplusf(r);
      int t = triOff(i) + (j - i);
      float sig = 1.f / (1.f + __expf(-r));
      val = sig * __expf((od[t] - sp) + ch[t] - Z);
    }
    Mb[idx] = val;
  }
}

extern "C" void kernel_launch(void* const* d_in, const int* in_sizes, int n_in,
                              void* d_out, int out_size, void* d_ws, size_t ws_size,
                              hipStream_t stream) {
  const float* rules = (const float*)d_in[0];   // (B,S,S,1) f32
  const int* lens = (const int*)d_in[1];        // (B,) i32
  float* outZ = (float*)d_out;                  // [0:16) = Z
  float* marg = (float*)d_out + BB;             // [16:) = marginal

  const int smem = 2 * TRI_SIZE * sizeof(float);   // 148992 B
  hipFuncSetAttribute(reinterpret_cast<const void*>(cky_fused),
                      hipFuncAttributeMaxDynamicSharedMemorySize, smem);
  cky_fused<<<BB, NT, smem, stream>>>(rules, lens, outZ, marg);
}

// Round 5
// 1465.852 us; speedup vs baseline: 1.2232x; 1.2232x over previous
//
#include <hip/hip_runtime.h>

// Fused CKY inside-outside (log semiring), B=16, S=192, one workgroup/batch.
// All reduction streams are row-contiguous and read as b128/float4:
//   inside : ch rows (LDS, skewed) + chT shifted-transpose rows (LDS)
//   outside: od rows + odT transpose rows (LDS, reusing inside buffers)
//            ch rows + chT rows re-read as float4 from global (own-XCD L2)
// Two-pass LSE folded into chunked online merge with terms held in registers.
//
// Layouts (all row bases 16B-aligned):
//  ch  row i: skew (i&3); ch[i][j] at rowOff(i) + j - 4*(i>>2); cap 192-4*(i>>2)
//  chT row j (shifted): ch[k+1][j] at offT(j) + k, k=0..j-1 (so both inside
//      streams are indexed by k and 16B-align at k%4==0 blocks)
//  odT/chTG row x (unshifted): val[a][x] at offTG(x) + a, a=0..x

#define SS 192
#define BB 16
#define NT 1024
#define NEGF (-1e30f)
#define CH_FLOATS 18816
#define CHT_FLOATS 18624
#define SMEM_FLOATS 37632   // od (18816) + odT (18816) in phase 2

__device__ __forceinline__ int rowOff(int i) {
  int q = i >> 2, r = i & 3;
  return 192 * i - 8 * q * q + 8 * q - 4 * r * q;
}
__device__ __forceinline__ int offT(int j) {   // shifted transpose rows
  int n = j - 1;
  if (n < 0) return 0;
  int m = n >> 2, r = n & 3;
  return 4 * (2 * m * (m + 1) + r * (m + 1));
}
__device__ __forceinline__ int offTG(int x) {  // unshifted transpose rows
  int m = x >> 2, r = x & 3;
  return 4 * (2 * m * (m + 1) + r * (m + 1));
}
__device__ __forceinline__ float softplusf(float x) {
  return fmaxf(x, 0.f) + log1pf(__expf(-fabsf(x)));
}
__device__ __forceinline__ int glogFor(int ncell, int nbMax) {
  int g1 = 31 - __clz(NT / ncell);                       // lanes available
  int g2 = (nbMax <= 1) ? 0 : (32 - __clz(nbMax - 1));   // ceil_log2(blocks)
  int g = g1 < g2 ? g1 : g2;
  if (g > 4) g = 4;
  if (g < 0) g = 0;
  return g;
}

__global__ __launch_bounds__(NT) void cky_fused(const float* __restrict__ rules,
                                                const int* __restrict__ lens,
                                                float* __restrict__ chG_,
                                                float* __restrict__ chTG_,
                                                float* __restrict__ outZ,
                                                float* __restrict__ marg) {
  extern __shared__ float lds[];
  float4* __restrict__ lds4 = reinterpret_cast<float4*>(lds);
  const int b = blockIdx.x;
  const int tid = threadIdx.x;
  const float* __restrict__ R = rules + (size_t)b * SS * SS;
  float* __restrict__ chG  = chG_  + (size_t)b * CH_FLOATS;
  float* __restrict__ chTG = chTG_ + (size_t)b * CH_FLOATS;

  // prologue: clear inside triangles (pads -> NEG), write diagonal
  for (int idx = tid; idx < CH_FLOATS + CHT_FLOATS; idx += NT) lds[idx] = NEGF;
  __syncthreads();
  for (int i = tid; i < SS; i += NT) {
    float sp = softplusf(R[i * SS + i]);
    lds[rowOff(i) + (i & 3)] = sp;                   // ch[i][i]
    if (i >= 1) lds[CH_FLOATS + offT(i) + (i - 1)] = sp;  // chT[i] slot i-1
  }
  __syncthreads();

  // ---------------- inside ----------------
  for (int w = 1; w < SS; ++w) {
    const int ncell = SS - w;
    const int Glog = glogFor(ncell, ((w + 2) >> 2) + 1);
    const int G = 1 << Glog;
    const int cell = tid >> Glog;
    const int lane = tid & (G - 1);
    if (cell < ncell) {
      const int i = cell, j = cell + w;
      const float r = R[i * SS + j];                 // prefetch (off crit path)
      const int t0 = i >> 2, t1 = (j - 1) >> 2;
      const int baseL = rowOff(i) - 4 * t0;          // + 4t = aligned slot
      const int baseR = CH_FLOATS + offT(j);
      float m = NEGF, s = 0.f;
      for (int u0 = t0 + lane; u0 <= t1; u0 += 4 * G) {
        float v[16];
        #pragma unroll
        for (int cc = 0; cc < 4; ++cc) {
          int t = u0 + cc * G;
          bool have = (t <= t1);
          int tc = have ? t : u0;
          float4 le = lds4[(unsigned)(baseL + 4 * tc) >> 2];
          float4 re = lds4[(unsigned)(baseR + 4 * tc) >> 2];
          int k0 = 4 * tc;
          v[4 * cc + 0] = (have && k0     >= i && k0     < j) ? le.x + re.x : NEGF;
          v[4 * cc + 1] = (have && k0 + 1 >= i && k0 + 1 < j) ? le.y + re.y : NEGF;
          v[4 * cc + 2] = (have && k0 + 2 >= i && k0 + 2 < j) ? le.z + re.z : NEGF;
          v[4 * cc + 3] = (have && k0 + 3 >= i && k0 + 3 < j) ? le.w + re.w : NEGF;
        }
        float mc = v[0];
        #pragma unroll
        for (int e = 1; e < 16; ++e) mc = fmaxf(mc, v[e]);
        float sc = 0.f;
        #pragma unroll
        for (int e = 0; e < 16; ++e) sc += __expf(v[e] - mc);
        float mn = fmaxf(m, mc);
        s = s * __expf(m - mn) + sc * __expf(mc - mn);
        m = mn;
      }
      for (int off = G >> 1; off; off >>= 1) {
        float m2 = __shfl_xor(m, off);
        float s2 = __shfl_xor(s, off);
        float mn = fmaxf(m, m2);
        s = s * __expf(m - mn) + s2 * __expf(m2 - mn);
        m = mn;
      }
      if (lane == 0) {
        float val = softplusf(r) + m + __logf(s);
        lds[rowOff(i) + j - 4 * t0] = val;
        if (i >= 1) lds[CH_FLOATS + offT(j) + (i - 1)] = val;
      }
    }
    __syncthreads();
  }

  const int L = lens[b];
  if (tid == 0) outZ[b] = lds[L - 1];                // ch[0][L-1]

  // ---------------- dump ch + chT to global (L2-resident) ----------------
  for (int idx = tid * 4; idx < CH_FLOATS; idx += NT * 4)
    *reinterpret_cast<float4*>(chG + idx) = lds4[idx >> 2];
  {
    const int wid = tid >> 6, ln = tid & 63;
    for (int x = wid; x < SS; x += NT / 64) {
      const int capT = (x + 4) & ~3;
      const int baseW = offTG(x);
      for (int a = ln; a < capT; a += 64) {
        float v = NEGF;
        if (a <= x) v = (a == 0) ? lds[x] : lds[CH_FLOATS + offT(x) + (a - 1)];
        chTG[baseW + a] = v;
      }
    }
  }
  __syncthreads();

  // ---------------- outside (od/odT reuse the LDS; root = sp) ----------------
  float* __restrict__ od  = lds;
  float* __restrict__ odT = lds + CH_FLOATS;
  if (tid == 0) {
    float sp = softplusf(R[L - 1]);                  // R[0][L-1]
    od[L - 1] = sp;
    odT[offTG(L - 1)] = sp;
  }
  __syncthreads();

  for (int w = L - 2; w >= 0; --w) {
    const int ncell = L - w;
    const int nterm = L - 1 - w;
    const int Glog = glogFor(ncell, ((nterm + 2) >> 2) + 2);
    const int G = 1 << Glog;
    const int cell = tid >> Glog;
    const int lane = tid & (G - 1);
    if (cell < ncell) {
      const int i = cell, j = cell + w;
      const float r = R[i * SS + j];
      const int t0P = (j + 1) >> 2;
      const int nbP = (j < L - 1) ? (((L - 1) >> 2) - t0P + 1) : 0;
      const int nbA = (i >= 1) ? (((i - 1) >> 2) + 1) : 0;
      const int nb = nbP + nbA;
      const int baseOdI   = rowOff(i) - 4 * (i >> 2);
      const int baseChJ1  = (j < L - 1) ? (rowOff(j + 1) - 4 * ((j + 1) >> 2)) : 0;
      const int baseOdTJ  = CH_FLOATS + offTG(j);
      const int baseChTI1 = (i >= 1) ? offTG(i - 1) : 0;
      float m = NEGF, s = 0.f;
      for (int u0 = lane; u0 < nb; u0 += 4 * G) {
        float v[16];
        #pragma unroll
        for (int cc = 0; cc < 4; ++cc) {
          int u = u0 + cc * G;
          bool have = (u < nb);
          int uc = have ? u : u0;
          float4 A, Bv;
          int idx0, lo, hi;
          if (uc < nbP) {                            // parent [i,p], left child
            int t = t0P + uc;
            A  = lds4[(unsigned)(baseOdI + 4 * t) >> 2];
            Bv = *reinterpret_cast<const float4*>(chG + baseChJ1 + 4 * t);
            idx0 = 4 * t; lo = j + 1; hi = L;
          } else {                                   // parent [a,j], right child
            int t = uc - nbP;
            A  = lds4[(unsigned)(baseOdTJ + 4 * t) >> 2];
            Bv = *reinterpret_cast<const float4*>(chTG + baseChTI1 + 4 * t);
            idx0 = 4 * t; lo = 0; hi = i;
          }
          v[4 * cc + 0] = (have && idx0     >= lo && idx0     < hi) ? A.x + Bv.x : NEGF;
          v[4 * cc + 1] = (have && idx0 + 1 >= lo && idx0 + 1 < hi) ? A.y + Bv.y : NEGF;
          v[4 * cc + 2] = (have && idx0 + 2 >= lo && idx0 + 2 < hi) ? A.z + Bv.z : NEGF;
          v[4 * cc + 3] = (have && idx0 + 3 >= lo && idx0 + 3 < hi) ? A.w + Bv.w : NEGF;
        }
        float mc = v[0];
        #pragma unroll
        for (int e = 1; e < 16; ++e) mc = fmaxf(mc, v[e]);
        float sc = 0.f;
        #pragma unroll
        for (int e = 0; e < 16; ++e) sc += __expf(v[e] - mc);
        float mn = fmaxf(m, mc);
        s = s * __expf(m - mn) + sc * __expf(mc - mn);
        m = mn;
      }
      for (int off = G >> 1; off; off >>= 1) {
        float m2 = __shfl_xor(m, off);
        float s2 = __shfl_xor(s, off);
        float mn = fmaxf(m, m2);
        s = s * __expf(m - mn) + s2 * __expf(m2 - mn);
        m = mn;
      }
      if (lane == 0) {
        float val = softplusf(r) + m + __logf(s);
        od[baseOdI + j] = val;                       // od[i][j]
        odT[offTG(j) + i] = val;
      }
    }
    __syncthreads();
  }

  // ---------------- marginals ----------------
  const float Z = chG[L - 1];
  float* __restrict__ Mb = marg + (size_t)b * SS * SS;
  for (int idx = tid; idx < SS * SS; idx += NT) {
    int i = idx / SS, j = idx - i * SS;
    float val = 0.f;
    if (i <= j && j < L) {
      float r = R[idx];
      float sp = softplusf(r);
      int slot = rowOff(i) + j - 4 * (i >> 2);
      float o = od[slot] - sp;
      float c = chG[slot];
      float sig = 1.f / (1.f + __expf(-r));
      val = sig * __expf(o + c - Z);
    }
    Mb[idx] = val;
  }
}

extern "C" void kernel_launch(void* const* d_in, const int* in_sizes, int n_in,
                              void* d_out, int out_size, void* d_ws, size_t ws_size,
                              hipStream_t stream) {
  const float* rules = (const float*)d_in[0];   // (B,S,S,1) f32
  const int* lens = (const int*)d_in[1];        // (B,) i32
  float* outZ = (float*)d_out;                  // [0:16) = Z
  float* marg = (float*)d_out + BB;             // [16:) = marginal

  float* chG_  = (float*)d_ws;                         // B * 18816
  float* chTG_ = chG_ + (size_t)BB * CH_FLOATS;        // B * 18816

  const int smem = SMEM_FLOATS * sizeof(float);        // 150528 B
  hipFuncSetAttribute(reinterpret_cast<const void*>(cky_fused),
                      hipFuncAttributeMaxDynamicSharedMemorySize, smem);
  cky_fused<<<BB, NT, smem, stream>>>(rules, lens, chG_, chTG_, outZ, marg);
}

// Round 7
// 1362.559 us; speedup vs baseline: 1.3159x; 1.0758x over previous
//
#include <hip/hip_runtime.h>

// Tiled (Valiant-style) CKY inside-outside, B=16, S=192. One workgroup/batch,
// 12 waves. Chart processed as 16x16 tiles over 12 tile-diagonals:
//   - interior phase: per-tile LSE reduction over completed span-tiles
//     (float4 row/broadcast streams), partial stored in the cell's own slot
//   - in-tile phase: 31 sub-diagonals resolved by ONE WAVE in lockstep
//     (no block barriers; same-wave DS ordering)
// __syncthreads() only between tile-diagonals: ~24 barriers instead of 382.
// LDS: one square SQ[192][196] (150528 B) holding ch (inside) then od (outside).
// ch dumped to global (chG row-major + chTG transposed) for the outside pass.

#define SS 192
#define BB 16
#define NT 768
#define TT 16
#define NTL 12
#define LDSW 196
#define NEGF (-1e30f)

__device__ __forceinline__ float softplusf(float x) {
  return fmaxf(x, 0.f) + log1pf(__expf(-fabsf(x)));
}
__device__ __forceinline__ void lse_merge(float& m, float& s, float m2, float s2) {
  float nm = fmaxf(m, m2);
  s = s * __expf(m - nm) + s2 * __expf(m2 - nm);
  m = nm;
}
__device__ __forceinline__ float f4c(const float4& v, int q) {
  switch (q) { case 0: return v.x; case 1: return v.y; case 2: return v.z; default: return v.w; }
}

__global__ __launch_bounds__(NT) void cky_tiled(const float* __restrict__ rules,
                                                const int* __restrict__ lens,
                                                float* __restrict__ chG_,
                                                float* __restrict__ chTG_,
                                                float* __restrict__ outZ,
                                                float* __restrict__ marg) {
  extern __shared__ float SQ[];
  float4* SQ4 = reinterpret_cast<float4*>(SQ);
  const int b = blockIdx.x;
  const int tid = threadIdx.x;
  const int wave = tid >> 6;
  const int lane = tid & 63;
  const int il = lane >> 2;   // interior mapping: row within tile
  const int jb = lane & 3;    // col block (4 cols per lane)
  const int cidx = lane >> 2; // substep mapping: cell index on sub-diagonal
  const int g = lane & 3;     // substep mapping: lane within cell group
  const float* __restrict__ R = rules + (size_t)b * SS * SS;
  float* __restrict__ chG  = chG_  + (size_t)b * SS * SS;
  float* __restrict__ chTG = chTG_ + (size_t)b * SS * SS;
  float4* chG4 = reinterpret_cast<float4*>(chG);
  const int L = lens[b];

  // ---------------- prologue ----------------
  for (int idx = tid; idx < SS * (LDSW / 4); idx += NT)
    SQ4[idx] = make_float4(NEGF, NEGF, NEGF, NEGF);
  __syncthreads();
  for (int i = tid; i < SS; i += NT)
    SQ[i * LDSW + i] = softplusf(R[i * SS + i]);
  __syncthreads();

  // ---------------- INSIDE: tile-diagonals ascending ----------------
  for (int d = 0; d < NTL; ++d) {
    if (wave < NTL - d) {
      const int I = wave, J = wave + d;
      const int gi = TT * I + il;
      const int cb = TT * J + 4 * jb;
      // ---- interior: K tiles strictly between I and J ----
      if (d >= 2) {
        float m[4] = {NEGF, NEGF, NEGF, NEGF};
        float s[4] = {0.f, 0.f, 0.f, 0.f};
        for (int K = I + 1; K < J; ++K) {
          const int k0 = TT * K;
          #pragma unroll
          for (int kb = 0; kb < 4; ++kb) {
            const int k = k0 + 4 * kb;
            float4 a4 = SQ4[(gi * LDSW + k) >> 2];
            float4 b0 = SQ4[((k + 1) * LDSW + cb) >> 2];
            float4 b1 = SQ4[((k + 2) * LDSW + cb) >> 2];
            float4 b2 = SQ4[((k + 3) * LDSW + cb) >> 2];
            float4 b3 = SQ4[((k + 4) * LDSW + cb) >> 2];
            #pragma unroll
            for (int q = 0; q < 4; ++q) {
              float v0 = a4.x + f4c(b0, q);
              float v1 = a4.y + f4c(b1, q);
              float v2 = a4.z + f4c(b2, q);
              float v3 = a4.w + f4c(b3, q);
              float bm = fmaxf(fmaxf(v0, v1), fmaxf(v2, v3));
              float bs = __expf(v0 - bm) + __expf(v1 - bm) +
                         __expf(v2 - bm) + __expf(v3 - bm);
              lse_merge(m[q], s[q], bm, bs);
            }
          }
        }
        float4 p4;
        p4.x = (m[0] < -1e29f) ? NEGF : m[0] + __logf(s[0]);
        p4.y = (m[1] < -1e29f) ? NEGF : m[1] + __logf(s[1]);
        p4.z = (m[2] < -1e29f) ? NEGF : m[2] + __logf(s[2]);
        p4.w = (m[3] < -1e29f) ? NEGF : m[3] + __logf(s[3]);
        SQ4[(gi * LDSW + cb) >> 2] = p4;   // partial into own slot
      }
      // ---- in-tile sequential: sub-diagonals ascending, one wave, no barrier
      const int s0 = (d == 0) ? TT : 0;    // diag tiles: skip s<=15 (diag preset)
      for (int st = s0; st <= 30; ++st) {
        int ilmin = 15 - st; if (ilmin < 0) ilmin = 0;
        int ilmax = 30 - st; if (ilmax > 15) ilmax = 15;
        int ncell = ilmax - ilmin + 1;
        bool active = (cidx < ncell);
        int ci = ilmin + (active ? cidx : 0);
        int cj = ci + st - 15;
        int cgi = TT * I + ci, cgj = TT * J + cj;
        float r = (active && g == 0) ? R[cgi * SS + cgj] : 0.f;  // prefetch
        int c1 = (d == 0) ? (st - 15) : (16 - ci);
        int c2 = (d == 0) ? 0 : cj;
        int nt = c1 + c2;
        float m, sa;
        if (g == 0) { m = SQ[cgi * LDSW + cgj]; sa = 1.f; }       // slot term
        else        { m = NEGF; sa = 0.f; }
        float tv[8];
        #pragma unroll
        for (int u = 0; u < 8; ++u) {
          int t = g + 4 * u;
          bool ok = active && (t < nt);
          int tc = ok ? t : 0;
          int k = (tc < c1) ? (cgi + tc) : (TT * J + (tc - c1));
          float v = SQ[cgi * LDSW + k] + SQ[(k + 1) * LDSW + cgj];
          tv[u] = ok ? v : NEGF;
        }
        float m0 = fmaxf(tv[0], tv[1]), m1 = fmaxf(tv[2], tv[3]);
        float m2 = fmaxf(tv[4], tv[5]), m3 = fmaxf(tv[6], tv[7]);
        float bm = fmaxf(fmaxf(m0, m1), fmaxf(m2, m3));
        float bs = (__expf(tv[0] - bm) + __expf(tv[1] - bm)) +
                   (__expf(tv[2] - bm) + __expf(tv[3] - bm)) +
                   (__expf(tv[4] - bm) + __expf(tv[5] - bm)) +
                   (__expf(tv[6] - bm) + __expf(tv[7] - bm));
        lse_merge(m, sa, bm, bs);
        lse_merge(m, sa, __shfl_xor(m, 1), __shfl_xor(sa, 1));
        lse_merge(m, sa, __shfl_xor(m, 2), __shfl_xor(sa, 2));
        if (active && g == 0)
          SQ[cgi * LDSW + cgj] = softplusf(r) + m + __logf(sa);
        __builtin_amdgcn_wave_barrier();
      }
    }
    __syncthreads();
  }

  // ---------------- Z + dump ch to global ----------------
  if (tid == 0) outZ[b] = SQ[L - 1];
  for (int idx = tid; idx < SS * 48; idx += NT) {
    int rr = idx / 48, cc = idx - rr * 48;
    chG4[rr * 48 + cc] = SQ4[rr * 49 + cc];
  }
  for (int idx = tid; idx < SS * SS; idx += NT) {
    int cc = idx / SS, rr = idx - cc * SS;
    chTG[idx] = SQ[rr * LDSW + cc];      // chTG[col][row] = ch[row][col]
  }
  __syncthreads();

  // ---------------- reinit SQ as od; root = sp ----------------
  for (int idx = tid; idx < SS * (LDSW / 4); idx += NT)
    SQ4[idx] = make_float4(NEGF, NEGF, NEGF, NEGF);
  __syncthreads();
  if (tid == 0) SQ[L - 1] = softplusf(R[L - 1]);
  __syncthreads();

  // ---------------- OUTSIDE: tile-diagonals descending ----------------
  for (int d = NTL - 1; d >= 0; --d) {
    const int I = wave, J = wave + d;
    if (wave < NTL - d && TT * J < L) {
      const int gi = TT * I + il;
      const int cb = TT * J + 4 * jb;
      // ---- interior: parents in completed tiles ----
      if (d <= 10) {
        float m[4] = {NEGF, NEGF, NEGF, NEGF};
        float s[4] = {0.f, 0.f, 0.f, 0.f};
        // left parents [i,p], p in tiles right of J
        for (int p0 = TT * (J + 1); p0 < SS; p0 += 4) {
          float4 o4 = SQ4[(gi * LDSW + p0) >> 2];
          #pragma unroll
          for (int q = 0; q < 4; ++q) {
            float4 c4 = chG4[((cb + q + 1) * SS + p0) >> 2];
            float v0 = o4.x + c4.x, v1 = o4.y + c4.y;
            float v2 = o4.z + c4.z, v3 = o4.w + c4.w;
            float bm = fmaxf(fmaxf(v0, v1), fmaxf(v2, v3));
            float bs = __expf(v0 - bm) + __expf(v1 - bm) +
                       __expf(v2 - bm) + __expf(v3 - bm);
            lse_merge(m[q], s[q], bm, bs);
          }
        }
        // right parents [a,j], a in tiles above I
        for (int a0 = 0; a0 < TT * I; a0 += 4) {
          float4 c4 = *reinterpret_cast<const float4*>(&chTG[(gi - 1) * SS + a0]);
          float4 o0 = SQ4[((a0 + 0) * LDSW + cb) >> 2];
          float4 o1 = SQ4[((a0 + 1) * LDSW + cb) >> 2];
          float4 o2 = SQ4[((a0 + 2) * LDSW + cb) >> 2];
          float4 o3 = SQ4[((a0 + 3) * LDSW + cb) >> 2];
          #pragma unroll
          for (int q = 0; q < 4; ++q) {
            float v0 = f4c(o0, q) + c4.x, v1 = f4c(o1, q) + c4.y;
            float v2 = f4c(o2, q) + c4.z, v3 = f4c(o3, q) + c4.w;
            float bm = fmaxf(fmaxf(v0, v1), fmaxf(v2, v3));
            float bs = __expf(v0 - bm) + __expf(v1 - bm) +
                       __expf(v2 - bm) + __expf(v3 - bm);
            lse_merge(m[q], s[q], bm, bs);
          }
        }
        #pragma unroll
        for (int q = 0; q < 4; ++q) {
          int cgj = cb + q;
          float pm = (m[q] < -1e29f) ? NEGF : m[q] + __logf(s[q]);
          if (!(gi == 0 && cgj == L - 1))          // never clobber the root
            SQ[gi * LDSW + cgj] = pm;
        }
      }
      // ---- in-tile sequential: sub-diagonals DESCENDING ----
      const int sEnd = (d == 0) ? 15 : 0;
      for (int st = 30; st >= sEnd; --st) {
        int ilmin = 15 - st; if (ilmin < 0) ilmin = 0;
        int ilmax = 30 - st; if (ilmax > 15) ilmax = 15;
        int ncell = ilmax - ilmin + 1;
        bool active = (cidx < ncell);
        int ci = ilmin + (active ? cidx : 0);
        int cj = ci + st - 15;
        int cgi = TT * I + ci, cgj = TT * J + cj;
        bool isroot = (cgi == 0 && cgj == L - 1);
        bool dowrite = active && (cgj < L) && !isroot;
        float r = (dowrite && g == 0) ? R[cgi * SS + cgj] : 0.f;
        int c1 = 15 - cj;     // left boundary p in [cgj+1, 16J+15]
        int c2 = ci;          // right boundary a in [16I, cgi-1]
        int nt = c1 + c2;
        float m, sa;
        if (g == 0) { m = SQ[cgi * LDSW + cgj]; sa = 1.f; }   // interior partial
        else        { m = NEGF; sa = 0.f; }
        float tv[8];
        #pragma unroll
        for (int u = 0; u < 8; ++u) {
          int t = g + 4 * u;
          bool ok = active && (t < nt);
          int tc = ok ? t : 0;
          float v;
          if (tc < c1) {
            int p = cgj + 1 + tc;
            v = SQ[cgi * LDSW + p] + chG[(cgj + 1) * SS + p];
          } else {
            int a = TT * I + (tc - c1);
            int rowT = cgi - 1; if (rowT < 0) rowT = 0;
            v = SQ[a * LDSW + cgj] + chTG[rowT * SS + a];
          }
          tv[u] = ok ? v : NEGF;
        }
        float m0 = fmaxf(tv[0], tv[1]), m1 = fmaxf(tv[2], tv[3]);
        float m2 = fmaxf(tv[4], tv[5]), m3 = fmaxf(tv[6], tv[7]);
        float bm = fmaxf(fmaxf(m0, m1), fmaxf(m2, m3));
        float bs = (__expf(tv[0] - bm) + __expf(tv[1] - bm)) +
                   (__expf(tv[2] - bm) + __expf(tv[3] - bm)) +
                   (__expf(tv[4] - bm) + __expf(tv[5] - bm)) +
                   (__expf(tv[6] - bm) + __expf(tv[7] - bm));
        lse_merge(m, sa, bm, bs);
        lse_merge(m, sa, __shfl_xor(m, 1), __shfl_xor(sa, 1));
        lse_merge(m, sa, __shfl_xor(m, 2), __shfl_xor(sa, 2));
        if (dowrite && g == 0)
          SQ[cgi * LDSW + cgj] = softplusf(r) + m + __logf(sa);
        __builtin_amdgcn_wave_barrier();
      }
    }
    __syncthreads();
  }

  // ---------------- marginals ----------------
  const float Z = chG[L - 1];
  float* __restrict__ Mb = marg + (size_t)b * SS * SS;
  for (int idx = tid; idx < SS * SS; idx += NT) {
    int i = idx / SS, j = idx - i * SS;
    float val = 0.f;
    if (i <= j && j < L) {
      float r = R[idx];
      float sp = softplusf(r);
      float o = SQ[i * LDSW + j] - sp;
      float c = chG[idx];
      float sig = 1.f / (1.f + __expf(-r));
      val = sig * __expf(o + c - Z);
    }
    Mb[idx] = val;
  }
}

extern "C" void kernel_launch(void* const* d_in, const int* in_sizes, int n_in,
                              void* d_out, int out_size, void* d_ws, size_t ws_size,
                              hipStream_t stream) {
  const float* rules = (const float*)d_in[0];   // (B,S,S,1) f32
  const int* lens = (const int*)d_in[1];        // (B,) i32
  float* outZ = (float*)d_out;                  // [0:16) = Z
  float* marg = (float*)d_out + BB;             // [16:) = marginal

  float* chG_  = (float*)d_ws;                        // B * 192*192
  float* chTG_ = chG_ + (size_t)BB * SS * SS;         // B * 192*192

  const int smem = SS * LDSW * sizeof(float);         // 150528 B
  hipFuncSetAttribute(reinterpret_cast<const void*>(cky_tiled),
                      hipFuncAttributeMaxDynamicSharedMemorySize, smem);
  cky_tiled<<<BB, NT, smem, stream>>>(rules, lens, chG_, chTG_, outZ, marg);
}

// Round 9
// 1251.116 us; speedup vs baseline: 1.4331x; 1.0891x over previous
//
#include <hip/hip_runtime.h>

// Tiled CKY inside-outside, B=16, S=192 — 3 dispatches for per-phase rocprof.
// LDS square SQ[192][196]; UPPER triangle = chart (ch / od). LOWER triangle +
// pad col 192 = mirrors that keep the serial sub-step chains 100% LDS:
//   sp(i,j)          at SQ[j][i]   (per-tile precompute, region used once)
//   ch diag tiles    at SQ[c][r] (r<c) and ch[r][r] at SQ[r][192] (outside)
// In-tile sub-diagonals: one wave, no block barriers. __syncthreads only
// between the 12 tile-diagonals of each pass.
// R8 bugfix: outside interior must write UPPER cells only (gi <= cgj) — at
// d=0 the unguarded write clobbered the diag-tile ch-mirrors before the
// same wave's in-tile chain read them (-> inf marginals).

#define SS 192
#define BB 16
#define NT 768
#define TT 16
#define NTL 12
#define LDSW 196
#define NEGF (-1e30f)

__device__ __forceinline__ float softplusf(float x) {
  return fmaxf(x, 0.f) + log1pf(__expf(-fabsf(x)));
}
__device__ __forceinline__ void lse_merge(float& m, float& s, float m2, float s2) {
  float nm = fmaxf(m, m2);
  s = s * __expf(m - nm) + s2 * __expf(m2 - nm);
  m = nm;
}
__device__ __forceinline__ float f4c(const float4& v, int q) {
  switch (q) { case 0: return v.x; case 1: return v.y; case 2: return v.z; default: return v.w; }
}

// ============================ INSIDE ============================
__global__ __launch_bounds__(NT) void cky_inside(const float* __restrict__ rules,
                                                 const int* __restrict__ lens,
                                                 float* __restrict__ chG_,
                                                 float* __restrict__ chTG_,
                                                 float* __restrict__ outZ) {
  extern __shared__ float SQ[];
  float4* SQ4 = reinterpret_cast<float4*>(SQ);
  const int b = blockIdx.x;
  const int tid = threadIdx.x;
  const int wave = tid >> 6;
  const int lane = tid & 63;
  const int il = lane >> 2;
  const int jb = lane & 3;
  const int cidx = lane >> 2;
  const int g = lane & 3;
  const float* __restrict__ R = rules + (size_t)b * SS * SS;
  float* __restrict__ chG  = chG_  + (size_t)b * SS * SS;
  float* __restrict__ chTG = chTG_ + (size_t)b * SS * SS;
  float4* chG4 = reinterpret_cast<float4*>(chG);
  const int L = lens[b];

  for (int idx = tid; idx < SS * (LDSW / 4); idx += NT)
    SQ4[idx] = make_float4(NEGF, NEGF, NEGF, NEGF);
  __syncthreads();
  for (int i = tid; i < SS; i += NT)
    SQ[i * LDSW + i] = softplusf(R[i * SS + i]);
  __syncthreads();

  for (int d = 0; d < NTL; ++d) {
    if (wave < NTL - d) {
      const int I = wave, J = wave + d;
      const int gi = TT * I + il;
      const int cb = TT * J + 4 * jb;
      // ---- sp-mirror precompute: sp(i,j) -> SQ[j][i] (lower) ----
      {
        int rr = lane >> 2, cblk = lane & 3;
        int gr = TT * I + rr, gc0 = TT * J + 4 * cblk;
        float4 rv = *reinterpret_cast<const float4*>(&R[gr * SS + gc0]);
        #pragma unroll
        for (int q = 0; q < 4; ++q) {
          int gc = gc0 + q;
          if (gc > gr) SQ[gc * LDSW + gr] = softplusf(f4c(rv, q));
        }
      }
      // ---- interior: K tiles strictly between I and J ----
      if (d >= 2) {
        float m[4] = {NEGF, NEGF, NEGF, NEGF};
        float s[4] = {0.f, 0.f, 0.f, 0.f};
        for (int K = I + 1; K < J; ++K) {
          const int k0 = TT * K;
          #pragma unroll
          for (int kb = 0; kb < 4; ++kb) {
            const int k = k0 + 4 * kb;
            float4 a4 = SQ4[(gi * LDSW + k) >> 2];
            float4 b0 = SQ4[((k + 1) * LDSW + cb) >> 2];
            float4 b1 = SQ4[((k + 2) * LDSW + cb) >> 2];
            float4 b2 = SQ4[((k + 3) * LDSW + cb) >> 2];
            float4 b3 = SQ4[((k + 4) * LDSW + cb) >> 2];
            #pragma unroll
            for (int q = 0; q < 4; ++q) {
              float v0 = a4.x + f4c(b0, q);
              float v1 = a4.y + f4c(b1, q);
              float v2 = a4.z + f4c(b2, q);
              float v3 = a4.w + f4c(b3, q);
              float bm = fmaxf(fmaxf(v0, v1), fmaxf(v2, v3));
              float bs = __expf(v0 - bm) + __expf(v1 - bm) +
                         __expf(v2 - bm) + __expf(v3 - bm);
              lse_merge(m[q], s[q], bm, bs);
            }
          }
        }
        float4 p4;
        p4.x = (m[0] < -1e29f) ? NEGF : m[0] + __logf(s[0]);
        p4.y = (m[1] < -1e29f) ? NEGF : m[1] + __logf(s[1]);
        p4.z = (m[2] < -1e29f) ? NEGF : m[2] + __logf(s[2]);
        p4.w = (m[3] < -1e29f) ? NEGF : m[3] + __logf(s[3]);
        SQ4[(gi * LDSW + cb) >> 2] = p4;
      }
      __builtin_amdgcn_wave_barrier();
      // ---- in-tile sub-diagonals (all-LDS serial chain) ----
      const int s0 = (d == 0) ? TT : 0;
      for (int st = s0; st <= 30; ++st) {
        int ilmin = 15 - st; if (ilmin < 0) ilmin = 0;
        int ilmax = 30 - st; if (ilmax > 15) ilmax = 15;
        int ncell = ilmax - ilmin + 1;
        bool active = (cidx < ncell);
        int ci = ilmin + (active ? cidx : 0);
        int cj = ci + st - 15;
        int cgi = TT * I + ci, cgj = TT * J + cj;
        int c1 = (d == 0) ? (st - 15) : (16 - ci);
        int c2 = (d == 0) ? 0 : cj;
        int nt = c1 + c2;
        float m, sa, spv = 0.f;
        if (g == 0) { m = SQ[cgi * LDSW + cgj]; sa = 1.f; spv = SQ[cgj * LDSW + cgi]; }
        else        { m = NEGF; sa = 0.f; }
        float tv[8];
        #pragma unroll
        for (int u = 0; u < 8; ++u) {
          int t = g + 4 * u;
          bool ok = active && (t < nt);
          int tc = ok ? t : 0;
          int k = (tc < c1) ? (cgi + tc) : (TT * J + (tc - c1));
          float v = SQ[cgi * LDSW + k] + SQ[(k + 1) * LDSW + cgj];
          tv[u] = ok ? v : NEGF;
        }
        float m0 = fmaxf(tv[0], tv[1]), m1 = fmaxf(tv[2], tv[3]);
        float m2 = fmaxf(tv[4], tv[5]), m3 = fmaxf(tv[6], tv[7]);
        float bm = fmaxf(fmaxf(m0, m1), fmaxf(m2, m3));
        float bs = (__expf(tv[0] - bm) + __expf(tv[1] - bm)) +
                   (__expf(tv[2] - bm) + __expf(tv[3] - bm)) +
                   (__expf(tv[4] - bm) + __expf(tv[5] - bm)) +
                   (__expf(tv[6] - bm) + __expf(tv[7] - bm));
        lse_merge(m, sa, bm, bs);
        lse_merge(m, sa, __shfl_xor(m, 1), __shfl_xor(sa, 1));
        lse_merge(m, sa, __shfl_xor(m, 2), __shfl_xor(sa, 2));
        if (active && g == 0)
          SQ[cgi * LDSW + cgj] = spv + m + __logf(sa);
        __builtin_amdgcn_wave_barrier();
      }
    }
    __syncthreads();
  }

  if (tid == 0) outZ[b] = SQ[L - 1];
  for (int idx = tid; idx < SS * 48; idx += NT) {
    int rr = idx / 48, cc = idx - rr * 48;
    chG4[rr * 48 + cc] = SQ4[rr * 49 + cc];
  }
  for (int idx = tid; idx < SS * SS; idx += NT) {
    int cc = idx / SS, rr = idx - cc * SS;
    chTG[idx] = SQ[rr * LDSW + cc];
  }
}

// ============================ OUTSIDE ============================
__global__ __launch_bounds__(NT) void cky_outside(const float* __restrict__ rules,
                                                  const int* __restrict__ lens,
                                                  const float* __restrict__ chG_,
                                                  const float* __restrict__ chTG_,
                                                  float* __restrict__ odG_) {
  extern __shared__ float SQ[];
  float4* SQ4 = reinterpret_cast<float4*>(SQ);
  const int b = blockIdx.x;
  const int tid = threadIdx.x;
  const int wave = tid >> 6;
  const int lane = tid & 63;
  const int il = lane >> 2;
  const int jb = lane & 3;
  const int cidx = lane >> 2;
  const int g = lane & 3;
  const float* __restrict__ R    = rules + (size_t)b * SS * SS;
  const float* __restrict__ chG  = chG_  + (size_t)b * SS * SS;
  const float* __restrict__ chTG = chTG_ + (size_t)b * SS * SS;
  const float4* chG4 = reinterpret_cast<const float4*>(chG);
  float* __restrict__ odG = odG_ + (size_t)b * SS * SS;
  float4* odG4 = reinterpret_cast<float4*>(odG);
  const int L = lens[b];

  for (int idx = tid; idx < SS * (LDSW / 4); idx += NT)
    SQ4[idx] = make_float4(NEGF, NEGF, NEGF, NEGF);
  __syncthreads();
  // prologue: mirror ch DIAG tiles into lower halves + pad col 192
  for (int idx = tid; idx < NTL * 256; idx += NT) {
    int T = idx >> 8, cell = idx & 255;
    int rr = cell >> 4, cc = cell & 15;
    int gr = TT * T + rr, gc = TT * T + cc;
    float v = chG[gr * SS + gc];
    if (rr < cc)       SQ[gc * LDSW + gr] = v;
    else if (rr == cc) SQ[gr * LDSW + 192] = v;
  }
  __syncthreads();
  if (tid == 0) SQ[L - 1] = softplusf(R[L - 1]);   // root: o=0 -> sp[0][L-1]
  __syncthreads();

  for (int d = NTL - 1; d >= 0; --d) {
    const int I = wave, J = wave + d;
    if (wave < NTL - d && TT * J < L) {
      const int gi = TT * I + il;
      const int cb = TT * J + 4 * jb;
      // ---- sp-mirror precompute (d>0; region (J,I) lower, used once) ----
      if (d > 0) {
        int rr = lane >> 2, cblk = lane & 3;
        int gr = TT * I + rr, gc0 = TT * J + 4 * cblk;
        float4 rv = *reinterpret_cast<const float4*>(&R[gr * SS + gc0]);
        #pragma unroll
        for (int q = 0; q < 4; ++q)
          SQ[(gc0 + q) * LDSW + gr] = softplusf(f4c(rv, q));
      }
      // ---- interior: parents in completed tiles (global ch streams) ----
      if (d <= 10) {
        float m[4] = {NEGF, NEGF, NEGF, NEGF};
        float s[4] = {0.f, 0.f, 0.f, 0.f};
        for (int p0 = TT * (J + 1); p0 < SS; p0 += 4) {
          float4 o4 = SQ4[(gi * LDSW + p0) >> 2];
          #pragma unroll
          for (int q = 0; q < 4; ++q) {
            float4 c4 = chG4[((cb + q + 1) * SS + p0) >> 2];
            float v0 = o4.x + c4.x, v1 = o4.y + c4.y;
            float v2 = o4.z + c4.z, v3 = o4.w + c4.w;
            float bm = fmaxf(fmaxf(v0, v1), fmaxf(v2, v3));
            float bs = __expf(v0 - bm) + __expf(v1 - bm) +
                       __expf(v2 - bm) + __expf(v3 - bm);
            lse_merge(m[q], s[q], bm, bs);
          }
        }
        for (int a0 = 0; a0 < TT * I; a0 += 4) {
          float4 c4 = *reinterpret_cast<const float4*>(&chTG[(gi - 1) * SS + a0]);
          float4 o0 = SQ4[((a0 + 0) * LDSW + cb) >> 2];
          float4 o1 = SQ4[((a0 + 1) * LDSW + cb) >> 2];
          float4 o2 = SQ4[((a0 + 2) * LDSW + cb) >> 2];
          float4 o3 = SQ4[((a0 + 3) * LDSW + cb) >> 2];
          #pragma unroll
          for (int q = 0; q < 4; ++q) {
            float v0 = f4c(o0, q) + c4.x, v1 = f4c(o1, q) + c4.y;
            float v2 = f4c(o2, q) + c4.z, v3 = f4c(o3, q) + c4.w;
            float bm = fmaxf(fmaxf(v0, v1), fmaxf(v2, v3));
            float bs = __expf(v0 - bm) + __expf(v1 - bm) +
                       __expf(v2 - bm) + __expf(v3 - bm);
            lse_merge(m[q], s[q], bm, bs);
          }
        }
        #pragma unroll
        for (int q = 0; q < 4; ++q) {
          int cgj = cb + q;
          float pm = (m[q] < -1e29f) ? NEGF : m[q] + __logf(s[q]);
          // BUGFIX: upper cells only — at d=0 the tile is a diag block and
          // an unguarded write clobbers the ch mirrors in the lower half.
          if (gi <= cgj && !(gi == 0 && cgj == L - 1))
            SQ[gi * LDSW + cgj] = pm;
        }
      }
      __builtin_amdgcn_wave_barrier();
      // ---- in-tile sub-diagonals DESCENDING (all-LDS chain) ----
      const int sEnd = (d == 0) ? 15 : 0;
      for (int st = 30; st >= sEnd; --st) {
        int ilmin = 15 - st; if (ilmin < 0) ilmin = 0;
        int ilmax = 30 - st; if (ilmax > 15) ilmax = 15;
        int ncell = ilmax - ilmin + 1;
        bool active = (cidx < ncell);
        int ci = ilmin + (active ? cidx : 0);
        int cj = ci + st - 15;
        int cgi = TT * I + ci, cgj = TT * J + cj;
        bool isroot = (cgi == 0 && cgj == L - 1);
        bool dowrite = active && (cgj < L) && !isroot;
        float r = (d == 0 && dowrite && g == 0) ? R[cgi * SS + cgj] : 0.f;
        int c1 = 15 - cj;
        int c2 = ci;
        int nt = c1 + c2;
        float m, sa, spv = 0.f;
        if (g == 0) {
          m = SQ[cgi * LDSW + cgj]; sa = 1.f;
          if (d > 0) spv = SQ[cgj * LDSW + cgi];
        } else { m = NEGF; sa = 0.f; }
        float tv[8];
        #pragma unroll
        for (int u = 0; u < 8; ++u) {
          int t = g + 4 * u;
          bool ok = active && (t < nt);
          int tc = ok ? t : 0;
          float v;
          if (tc < c1) {
            int p = cgj + 1 + tc;
            int cA = (p == cgj + 1) ? 192 : (cgj + 1);
            v = SQ[cgi * LDSW + p] + SQ[p * LDSW + cA];
          } else {
            int a = TT * I + (tc - c1);
            int rm = cgi - 1; if (rm < 0) rm = 0;
            int cB = (a == rm) ? 192 : a;
            v = SQ[a * LDSW + cgj] + SQ[rm * LDSW + cB];
          }
          tv[u] = ok ? v : NEGF;
        }
        float m0 = fmaxf(tv[0], tv[1]), m1 = fmaxf(tv[2], tv[3]);
        float m2 = fmaxf(tv[4], tv[5]), m3 = fmaxf(tv[6], tv[7]);
        float bm = fmaxf(fmaxf(m0, m1), fmaxf(m2, m3));
        float bs = (__expf(tv[0] - bm) + __expf(tv[1] - bm)) +
                   (__expf(tv[2] - bm) + __expf(tv[3] - bm)) +
                   (__expf(tv[4] - bm) + __expf(tv[5] - bm)) +
                   (__expf(tv[6] - bm) + __expf(tv[7] - bm));
        lse_merge(m, sa, bm, bs);
        lse_merge(m, sa, __shfl_xor(m, 1), __shfl_xor(sa, 1));
        lse_merge(m, sa, __shfl_xor(m, 2), __shfl_xor(sa, 2));
        if (dowrite && g == 0)
          SQ[cgi * LDSW + cgj] = ((d == 0) ? softplusf(r) : spv) + m + __logf(sa);
        __builtin_amdgcn_wave_barrier();
      }
    }
    __syncthreads();
  }

  // dump od (upper square) for the marginal kernel
  for (int idx = tid; idx < SS * 48; idx += NT) {
    int rr = idx / 48, cc = idx - rr * 48;
    odG4[rr * 48 + cc] = SQ4[rr * 49 + cc];
  }
}

// ============================ MARGINALS ============================
__global__ __launch_bounds__(256) void cky_marg(const float* __restrict__ rules,
                                                const int* __restrict__ lens,
                                                const float* __restrict__ chG_,
                                                const float* __restrict__ odG_,
                                                float* __restrict__ marg) {
  const int total = BB * SS * SS;
  for (int idx = blockIdx.x * 256 + threadIdx.x; idx < total; idx += gridDim.x * 256) {
    int b = idx / (SS * SS);
    int rem = idx - b * SS * SS;
    int i = rem / SS, j = rem - i * SS;
    int L = lens[b];
    float val = 0.f;
    if (i <= j && j < L) {
      float r = rules[idx];
      float sp = softplusf(r);
      float Z = chG_[(size_t)b * SS * SS + (L - 1)];
      float o = odG_[idx] - sp;
      float c = chG_[idx];
      float sig = 1.f / (1.f + __expf(-r));
      val = sig * __expf(o + c - Z);
    }
    marg[idx] = val;
  }
}

extern "C" void kernel_launch(void* const* d_in, const int* in_sizes, int n_in,
                              void* d_out, int out_size, void* d_ws, size_t ws_size,
                              hipStream_t stream) {
  const float* rules = (const float*)d_in[0];   // (B,S,S,1) f32
  const int* lens = (const int*)d_in[1];        // (B,) i32
  float* outZ = (float*)d_out;                  // [0:16) = Z
  float* marg = (float*)d_out + BB;             // [16:) = marginal

  float* chG_  = (float*)d_ws;                        // B*S*S
  float* chTG_ = chG_ + (size_t)BB * SS * SS;         // B*S*S
  float* odG_  = chTG_ + (size_t)BB * SS * SS;        // B*S*S

  const int smem = SS * LDSW * sizeof(float);         // 150528 B
  hipFuncSetAttribute(reinterpret_cast<const void*>(cky_inside),
                      hipFuncAttributeMaxDynamicSharedMemorySize, smem);
  hipFuncSetAttribute(reinterpret_cast<const void*>(cky_outside),
                      hipFuncAttributeMaxDynamicSharedMemorySize, smem);

  cky_inside<<<BB, NT, smem, stream>>>(rules, lens, chG_, chTG_, outZ);
  cky_outside<<<BB, NT, smem, stream>>>(rules, lens, chG_, chTG_, odG_);
  cky_marg<<<(BB * SS * SS + 255) / 256, 256, 0, stream>>>(rules, lens, chG_, odG_, marg);
}

// Round 11
// 1201.039 us; speedup vs baseline: 1.4928x; 1.0417x over previous
//
#include <hip/hip_runtime.h>

// Tiled CKY inside-outside, B=16, S=192 — 3 dispatches (per-phase rocprof).
// Same structure as R9 (passing) with chain-latency fixes:
//  - G=4 LSE merges via quad_perm DPP (VALU pipe) instead of __shfl_xor
//    (ds_swizzle/LDS pipe): removes 2 serial LDS round-trips per substep.
//  - __syncthreads() between interior phase and in-tile chain phase each
//    diagonal: chains no longer contend with interior b128 streams.
//  - slot/sp reads made non-divergent (broadcast read + select).

#define SS 192
#define BB 16
#define NT 768
#define TT 16
#define NTL 12
#define LDSW 196
#define NEGF (-1e30f)

__device__ __forceinline__ float softplusf(float x) {
  return fmaxf(x, 0.f) + log1pf(__expf(-fabsf(x)));
}
__device__ __forceinline__ void lse_merge(float& m, float& s, float m2, float s2) {
  float nm = fmaxf(m, m2);
  s = s * __expf(m - nm) + s2 * __expf(m2 - nm);
  m = nm;
}
__device__ __forceinline__ float f4c(const float4& v, int q) {
  switch (q) { case 0: return v.x; case 1: return v.y; case 2: return v.z; default: return v.w; }
}
template <int CTRL>
__device__ __forceinline__ float dppf(float x) {   // quad_perm cross-lane, VALU pipe
  return __int_as_float(__builtin_amdgcn_update_dpp(
      0, __float_as_int(x), CTRL, 0xF, 0xF, true));
}
// 0xB1 = quad_perm [1,0,3,2] (xor 1);  0x4E = quad_perm [2,3,0,1] (xor 2)

// ============================ INSIDE ============================
__global__ __launch_bounds__(NT) void cky_inside(const float* __restrict__ rules,
                                                 const int* __restrict__ lens,
                                                 float* __restrict__ chG_,
                                                 float* __restrict__ chTG_,
                                                 float* __restrict__ outZ) {
  extern __shared__ float SQ[];
  float4* SQ4 = reinterpret_cast<float4*>(SQ);
  const int b = blockIdx.x;
  const int tid = threadIdx.x;
  const int wave = tid >> 6;
  const int lane = tid & 63;
  const int il = lane >> 2;
  const int jb = lane & 3;
  const int cidx = lane >> 2;
  const int g = lane & 3;
  const float* __restrict__ R = rules + (size_t)b * SS * SS;
  float* __restrict__ chG  = chG_  + (size_t)b * SS * SS;
  float* __restrict__ chTG = chTG_ + (size_t)b * SS * SS;
  float4* chG4 = reinterpret_cast<float4*>(chG);
  const int L = lens[b];

  for (int idx = tid; idx < SS * (LDSW / 4); idx += NT)
    SQ4[idx] = make_float4(NEGF, NEGF, NEGF, NEGF);
  __syncthreads();
  for (int i = tid; i < SS; i += NT)
    SQ[i * LDSW + i] = softplusf(R[i * SS + i]);
  __syncthreads();

  for (int d = 0; d < NTL; ++d) {
    const bool active = (wave < NTL - d);
    const int I = wave, J = wave + d;
    const int gi = TT * I + il;
    const int cb = TT * J + 4 * jb;
    if (active) {
      // ---- sp-mirror precompute: sp(i,j) -> SQ[j][i] (lower) ----
      {
        int rr = lane >> 2, cblk = lane & 3;
        int gr = TT * I + rr, gc0 = TT * J + 4 * cblk;
        float4 rv = *reinterpret_cast<const float4*>(&R[gr * SS + gc0]);
        #pragma unroll
        for (int q = 0; q < 4; ++q) {
          int gc = gc0 + q;
          if (gc > gr) SQ[gc * LDSW + gr] = softplusf(f4c(rv, q));
        }
      }
      // ---- interior: K tiles strictly between I and J ----
      if (d >= 2) {
        float m[4] = {NEGF, NEGF, NEGF, NEGF};
        float s[4] = {0.f, 0.f, 0.f, 0.f};
        for (int K = I + 1; K < J; ++K) {
          const int k0 = TT * K;
          #pragma unroll
          for (int kb = 0; kb < 4; ++kb) {
            const int k = k0 + 4 * kb;
            float4 a4 = SQ4[(gi * LDSW + k) >> 2];
            float4 b0 = SQ4[((k + 1) * LDSW + cb) >> 2];
            float4 b1 = SQ4[((k + 2) * LDSW + cb) >> 2];
            float4 b2 = SQ4[((k + 3) * LDSW + cb) >> 2];
            float4 b3 = SQ4[((k + 4) * LDSW + cb) >> 2];
            #pragma unroll
            for (int q = 0; q < 4; ++q) {
              float v0 = a4.x + f4c(b0, q);
              float v1 = a4.y + f4c(b1, q);
              float v2 = a4.z + f4c(b2, q);
              float v3 = a4.w + f4c(b3, q);
              float bm = fmaxf(fmaxf(v0, v1), fmaxf(v2, v3));
              float bs = __expf(v0 - bm) + __expf(v1 - bm) +
                         __expf(v2 - bm) + __expf(v3 - bm);
              lse_merge(m[q], s[q], bm, bs);
            }
          }
        }
        float4 p4;
        p4.x = (m[0] < -1e29f) ? NEGF : m[0] + __logf(s[0]);
        p4.y = (m[1] < -1e29f) ? NEGF : m[1] + __logf(s[1]);
        p4.z = (m[2] < -1e29f) ? NEGF : m[2] + __logf(s[2]);
        p4.w = (m[3] < -1e29f) ? NEGF : m[3] + __logf(s[3]);
        SQ4[(gi * LDSW + cb) >> 2] = p4;
      }
    }
    __syncthreads();                      // isolate chains from interior traffic
    if (active) {
      // ---- in-tile sub-diagonals (all-LDS serial chain) ----
      const int s0 = (d == 0) ? TT : 0;
      for (int st = s0; st <= 30; ++st) {
        int ilmin = 15 - st; if (ilmin < 0) ilmin = 0;
        int ilmax = 30 - st; if (ilmax > 15) ilmax = 15;
        int ncell = ilmax - ilmin + 1;
        bool act = (cidx < ncell);
        int ci = ilmin + (act ? cidx : 0);
        int cj = ci + st - 15;
        int cgi = TT * I + ci, cgj = TT * J + cj;
        int c1 = (d == 0) ? (st - 15) : (16 - ci);
        int c2 = (d == 0) ? 0 : cj;
        int nt = c1 + c2;
        float slotv = SQ[cgi * LDSW + cgj];        // broadcast within quad
        float spv   = SQ[cgj * LDSW + cgi];
        float m  = (g == 0) ? slotv : NEGF;
        float sa = (g == 0) ? 1.f : 0.f;
        float tv[8];
        #pragma unroll
        for (int u = 0; u < 8; ++u) {
          int t = g + 4 * u;
          bool ok = act && (t < nt);
          int tc = ok ? t : 0;
          int k = (tc < c1) ? (cgi + tc) : (TT * J + (tc - c1));
          float v = SQ[cgi * LDSW + k] + SQ[(k + 1) * LDSW + cgj];
          tv[u] = ok ? v : NEGF;
        }
        float m0 = fmaxf(tv[0], tv[1]), m1 = fmaxf(tv[2], tv[3]);
        float m2 = fmaxf(tv[4], tv[5]), m3 = fmaxf(tv[6], tv[7]);
        float bm = fmaxf(fmaxf(m0, m1), fmaxf(m2, m3));
        float bs = (__expf(tv[0] - bm) + __expf(tv[1] - bm)) +
                   (__expf(tv[2] - bm) + __expf(tv[3] - bm)) +
                   (__expf(tv[4] - bm) + __expf(tv[5] - bm)) +
                   (__expf(tv[6] - bm) + __expf(tv[7] - bm));
        lse_merge(m, sa, bm, bs);
        lse_merge(m, sa, dppf<0xB1>(m), dppf<0xB1>(sa));   // xor 1 (VALU)
        lse_merge(m, sa, dppf<0x4E>(m), dppf<0x4E>(sa));   // xor 2 (VALU)
        if (act && g == 0)
          SQ[cgi * LDSW + cgj] = spv + m + __logf(sa);
        __builtin_amdgcn_wave_barrier();
      }
    }
    __syncthreads();
  }

  if (tid == 0) outZ[b] = SQ[L - 1];
  for (int idx = tid; idx < SS * 48; idx += NT) {
    int rr = idx / 48, cc = idx - rr * 48;
    chG4[rr * 48 + cc] = SQ4[rr * 49 + cc];
  }
  for (int idx = tid; idx < SS * SS; idx += NT) {
    int cc = idx / SS, rr = idx - cc * SS;
    chTG[idx] = SQ[rr * LDSW + cc];
  }
}

// ============================ OUTSIDE ============================
__global__ __launch_bounds__(NT) void cky_outside(const float* __restrict__ rules,
                                                  const int* __restrict__ lens,
                                                  const float* __restrict__ chG_,
                                                  const float* __restrict__ chTG_,
                                                  float* __restrict__ odG_) {
  extern __shared__ float SQ[];
  float4* SQ4 = reinterpret_cast<float4*>(SQ);
  const int b = blockIdx.x;
  const int tid = threadIdx.x;
  const int wave = tid >> 6;
  const int lane = tid & 63;
  const int il = lane >> 2;
  const int jb = lane & 3;
  const int cidx = lane >> 2;
  const int g = lane & 3;
  const float* __restrict__ R    = rules + (size_t)b * SS * SS;
  const float* __restrict__ chG  = chG_  + (size_t)b * SS * SS;
  const float* __restrict__ chTG = chTG_ + (size_t)b * SS * SS;
  const float4* chG4 = reinterpret_cast<const float4*>(chG);
  float* __restrict__ odG = odG_ + (size_t)b * SS * SS;
  float4* odG4 = reinterpret_cast<float4*>(odG);
  const int L = lens[b];

  for (int idx = tid; idx < SS * (LDSW / 4); idx += NT)
    SQ4[idx] = make_float4(NEGF, NEGF, NEGF, NEGF);
  __syncthreads();
  // prologue: mirror ch DIAG tiles into lower halves + pad col 192
  for (int idx = tid; idx < NTL * 256; idx += NT) {
    int T = idx >> 8, cell = idx & 255;
    int rr = cell >> 4, cc = cell & 15;
    int gr = TT * T + rr, gc = TT * T + cc;
    float v = chG[gr * SS + gc];
    if (rr < cc)       SQ[gc * LDSW + gr] = v;
    else if (rr == cc) SQ[gr * LDSW + 192] = v;
  }
  __syncthreads();
  if (tid == 0) SQ[L - 1] = softplusf(R[L - 1]);   // root: o=0 -> sp[0][L-1]
  __syncthreads();

  for (int d = NTL - 1; d >= 0; --d) {
    const int I = wave, J = wave + d;
    const bool active = (wave < NTL - d) && (TT * J < L);
    const int gi = TT * I + il;
    const int cb = TT * J + 4 * jb;
    if (active) {
      // ---- sp-mirror precompute (d>0; region (J,I) lower, used once) ----
      if (d > 0) {
        int rr = lane >> 2, cblk = lane & 3;
        int gr = TT * I + rr, gc0 = TT * J + 4 * cblk;
        float4 rv = *reinterpret_cast<const float4*>(&R[gr * SS + gc0]);
        #pragma unroll
        for (int q = 0; q < 4; ++q)
          SQ[(gc0 + q) * LDSW + gr] = softplusf(f4c(rv, q));
      }
      // ---- interior: parents in completed tiles (global ch streams) ----
      if (d <= 10) {
        float m[4] = {NEGF, NEGF, NEGF, NEGF};
        float s[4] = {0.f, 0.f, 0.f, 0.f};
        for (int p0 = TT * (J + 1); p0 < SS; p0 += 4) {
          float4 o4 = SQ4[(gi * LDSW + p0) >> 2];
          #pragma unroll
          for (int q = 0; q < 4; ++q) {
            float4 c4 = chG4[((cb + q + 1) * SS + p0) >> 2];
            float v0 = o4.x + c4.x, v1 = o4.y + c4.y;
            float v2 = o4.z + c4.z, v3 = o4.w + c4.w;
            float bm = fmaxf(fmaxf(v0, v1), fmaxf(v2, v3));
            float bs = __expf(v0 - bm) + __expf(v1 - bm) +
                       __expf(v2 - bm) + __expf(v3 - bm);
            lse_merge(m[q], s[q], bm, bs);
          }
        }
        for (int a0 = 0; a0 < TT * I; a0 += 4) {
          float4 c4 = *reinterpret_cast<const float4*>(&chTG[(gi - 1) * SS + a0]);
          float4 o0 = SQ4[((a0 + 0) * LDSW + cb) >> 2];
          float4 o1 = SQ4[((a0 + 1) * LDSW + cb) >> 2];
          float4 o2 = SQ4[((a0 + 2) * LDSW + cb) >> 2];
          float4 o3 = SQ4[((a0 + 3) * LDSW + cb) >> 2];
          #pragma unroll
          for (int q = 0; q < 4; ++q) {
            float v0 = f4c(o0, q) + c4.x, v1 = f4c(o1, q) + c4.y;
            float v2 = f4c(o2, q) + c4.z, v3 = f4c(o3, q) + c4.w;
            float bm = fmaxf(fmaxf(v0, v1), fmaxf(v2, v3));
            float bs = __expf(v0 - bm) + __expf(v1 - bm) +
                       __expf(v2 - bm) + __expf(v3 - bm);
            lse_merge(m[q], s[q], bm, bs);
          }
        }
        #pragma unroll
        for (int q = 0; q < 4; ++q) {
          int cgj = cb + q;
          float pm = (m[q] < -1e29f) ? NEGF : m[q] + __logf(s[q]);
          // upper cells only (diag tiles carry ch mirrors in the lower half)
          if (gi <= cgj && !(gi == 0 && cgj == L - 1))
            SQ[gi * LDSW + cgj] = pm;
        }
      }
    }
    __syncthreads();                      // isolate chains from interior traffic
    if (active) {
      // ---- in-tile sub-diagonals DESCENDING (all-LDS chain) ----
      const int sEnd = (d == 0) ? 15 : 0;
      for (int st = 30; st >= sEnd; --st) {
        int ilmin = 15 - st; if (ilmin < 0) ilmin = 0;
        int ilmax = 30 - st; if (ilmax > 15) ilmax = 15;
        int ncell = ilmax - ilmin + 1;
        bool act = (cidx < ncell);
        int ci = ilmin + (act ? cidx : 0);
        int cj = ci + st - 15;
        int cgi = TT * I + ci, cgj = TT * J + cj;
        bool isroot = (cgi == 0 && cgj == L - 1);
        bool dowrite = act && (cgj < L) && !isroot;
        float r = (d == 0 && dowrite && g == 0) ? R[cgi * SS + cgj] : 0.f;
        int c1 = 15 - cj;
        int c2 = ci;
        int nt = c1 + c2;
        float slotv = SQ[cgi * LDSW + cgj];
        float spv   = (d > 0) ? SQ[cgj * LDSW + cgi] : 0.f;
        float m  = (g == 0) ? slotv : NEGF;
        float sa = (g == 0) ? 1.f : 0.f;
        float tv[8];
        #pragma unroll
        for (int u = 0; u < 8; ++u) {
          int t = g + 4 * u;
          bool ok = act && (t < nt);
          int tc = ok ? t : 0;
          float v;
          if (tc < c1) {
            int p = cgj + 1 + tc;
            int cA = (p == cgj + 1) ? 192 : (cgj + 1);
            v = SQ[cgi * LDSW + p] + SQ[p * LDSW + cA];
          } else {
            int a = TT * I + (tc - c1);
            int rm = cgi - 1; if (rm < 0) rm = 0;
            int cB = (a == rm) ? 192 : a;
            v = SQ[a * LDSW + cgj] + SQ[rm * LDSW + cB];
          }
          tv[u] = ok ? v : NEGF;
        }
        float m0 = fmaxf(tv[0], tv[1]), m1 = fmaxf(tv[2], tv[3]);
        float m2 = fmaxf(tv[4], tv[5]), m3 = fmaxf(tv[6], tv[7]);
        float bm = fmaxf(fmaxf(m0, m1), fmaxf(m2, m3));
        float bs = (__expf(tv[0] - bm) + __expf(tv[1] - bm)) +
                   (__expf(tv[2] - bm) + __expf(tv[3] - bm)) +
                   (__expf(tv[4] - bm) + __expf(tv[5] - bm)) +
                   (__expf(tv[6] - bm) + __expf(tv[7] - bm));
        lse_merge(m, sa, bm, bs);
        lse_merge(m, sa, dppf<0xB1>(m), dppf<0xB1>(sa));   // xor 1 (VALU)
        lse_merge(m, sa, dppf<0x4E>(m), dppf<0x4E>(sa));   // xor 2 (VALU)
        if (dowrite && g == 0)
          SQ[cgi * LDSW + cgj] = ((d == 0) ? softplusf(r) : spv) + m + __logf(sa);
        __builtin_amdgcn_wave_barrier();
      }
    }
    __syncthreads();
  }

  // dump od (upper square) for the marginal kernel
  for (int idx = tid; idx < SS * 48; idx += NT) {
    int rr = idx / 48, cc = idx - rr * 48;
    odG4[rr * 48 + cc] = SQ4[rr * 49 + cc];
  }
}

// ============================ MARGINALS ============================
__global__ __launch_bounds__(256) void cky_marg(const float* __restrict__ rules,
                                                const int* __restrict__ lens,
                                                const float* __restrict__ chG_,
                                                const float* __restrict__ odG_,
                                                float* __restrict__ marg) {
  const int total = BB * SS * SS;
  for (int idx = blockIdx.x * 256 + threadIdx.x; idx < total; idx += gridDim.x * 256) {
    int b = idx / (SS * SS);
    int rem = idx - b * SS * SS;
    int i = rem / SS, j = rem - i * SS;
    int L = lens[b];
    float val = 0.f;
    if (i <= j && j < L) {
      float r = rules[idx];
      float sp = softplusf(r);
      float Z = chG_[(size_t)b * SS * SS + (L - 1)];
      float o = odG_[idx] - sp;
      float c = chG_[idx];
      float sig = 1.f / (1.f + __expf(-r));
      val = sig * __expf(o + c - Z);
    }
    marg[idx] = val;
  }
}

extern "C" void kernel_launch(void* const* d_in, const int* in_sizes, int n_in,
                              void* d_out, int out_size, void* d_ws, size_t ws_size,
                              hipStream_t stream) {
  const float* rules = (const float*)d_in[0];   // (B,S,S,1) f32
  const int* lens = (const int*)d_in[1];        // (B,) i32
  float* outZ = (float*)d_out;                  // [0:16) = Z
  float* marg = (float*)d_out + BB;             // [16:) = marginal

  float* chG_  = (float*)d_ws;                        // B*S*S
  float* chTG_ = chG_ + (size_t)BB * SS * SS;         // B*S*S
  float* odG_  = chTG_ + (size_t)BB * SS * SS;        // B*S*S

  const int smem = SS * LDSW * sizeof(float);         // 150528 B
  hipFuncSetAttribute(reinterpret_cast<const void*>(cky_inside),
                      hipFuncAttributeMaxDynamicSharedMemorySize, smem);
  hipFuncSetAttribute(reinterpret_cast<const void*>(cky_outside),
                      hipFuncAttributeMaxDynamicSharedMemorySize, smem);

  cky_inside<<<BB, NT, smem, stream>>>(rules, lens, chG_, chTG_, outZ);
  cky_outside<<<BB, NT, smem, stream>>>(rules, lens, chG_, chTG_, odG_);
  cky_marg<<<(BB * SS * SS + 255) / 256, 256, 0, stream>>>(rules, lens, chG_, odG_, marg);
}

// Round 12
// 931.538 us; speedup vs baseline: 1.9247x; 1.2893x over previous
//
#include <hip/hip_runtime.h>

// CKY inside-outside, B=16, S=192 — per-tile-diagonal launches.
// Block = (batch, tile) of a tile-diagonal; 256 threads.
//   interior: thread-per-cell LSE partial over completed tiles, read from
//             global (row-major chG/odG + transposed chTG/odTG), -> LDS P.
//   chain   : wave 0 resolves the 31 in-tile sub-diagonals in private LDS
//             (A, Bt, brow, SP, P, T ~ 5.5 KB), DPP quad merges.
// Stream order between launches replaces per-diagonal __syncthreads.
// Charts live in global; lower triangles never read (odG NEG-initialized).

#define SS 192
#define BB 16
#define TT 16
#define NTL 12
#define NEGF (-1e30f)

__device__ __forceinline__ float softplusf(float x) {
  return fmaxf(x, 0.f) + log1pf(__expf(-fabsf(x)));
}
__device__ __forceinline__ void lse_merge(float& m, float& s, float m2, float s2) {
  float nm = fmaxf(m, m2);
  s = s * __expf(m - nm) + s2 * __expf(m2 - nm);
  m = nm;
}
template <int CTRL>
__device__ __forceinline__ float dppf(float x) {   // quad_perm cross-lane (VALU)
  return __int_as_float(__builtin_amdgcn_update_dpp(
      0, __float_as_int(x), CTRL, 0xF, 0xF, true));
}
// 0xB1 = quad_perm xor1, 0x4E = quad_perm xor2

// ---------------- init: NEG-fill odG/odTG ----------------
__global__ __launch_bounds__(256) void init_od(float* __restrict__ odG,
                                               float* __restrict__ odTG) {
  const int n4 = BB * SS * SS / 4;
  float4 nf = make_float4(NEGF, NEGF, NEGF, NEGF);
  float4* a = reinterpret_cast<float4*>(odG);
  float4* c = reinterpret_cast<float4*>(odTG);
  for (int i = blockIdx.x * 256 + threadIdx.x; i < n4; i += gridDim.x * 256) {
    a[i] = nf; c[i] = nf;
  }
}

// ---------------- INSIDE, one tile-diagonal ----------------
__global__ __launch_bounds__(256) void inside_diag(const float* __restrict__ rules,
                                                   float* __restrict__ chG_,
                                                   float* __restrict__ chTG_,
                                                   int d) {
  const int ntiles = NTL - d;
  const int b = blockIdx.x / ntiles;
  const int I = blockIdx.x % ntiles;
  const int J = I + d;
  const int tid = threadIdx.x;
  const int ci = tid >> 4, cj = tid & 15;
  const int gi = TT * I + ci, gj = TT * J + cj;
  const float* __restrict__ R = rules + (size_t)b * SS * SS;
  float* __restrict__ chG  = chG_  + (size_t)b * SS * SS;
  float* __restrict__ chTG = chTG_ + (size_t)b * SS * SS;

  __shared__ float A[TT][TT + 1], Bt[TT][TT + 1], T[TT][TT + 1];
  __shared__ float P[TT][TT + 1], SP[TT][TT + 1];
  __shared__ float brow[TT];

  const float spv_own = softplusf(R[gi * SS + gj]);
  SP[ci][cj] = spv_own;
  T[ci][cj] = (d == 0 && ci == cj) ? spv_own : NEGF;
  if (d >= 1) {
    A[ci][cj]  = chG[(TT * I + ci) * SS + TT * I + cj];
    Bt[ci][cj] = chG[(TT * J + ci) * SS + TT * J + cj];
  }
  if (d >= 2 && tid < TT) brow[tid] = chG[(TT * (I + 1)) * SS + TT * J + tid];

  // interior partial over k in [16(I+1), 16J)
  {
    float m = NEGF, s = 0.f;
    const float* chRow  = chG  + gi * SS;
    const float* chTRow = chTG + gj * SS;
    const int k0 = TT * (I + 1), k1 = TT * J;
    if (k0 < k1) {
      float4 blo = *reinterpret_cast<const float4*>(chTRow + k0);
      for (int k = k0; k < k1; k += 4) {
        float4 a4  = *reinterpret_cast<const float4*>(chRow + k);
        float4 bhi = *reinterpret_cast<const float4*>(chTRow + k + 4);
        float v0 = a4.x + blo.y, v1 = a4.y + blo.z;
        float v2 = a4.z + blo.w, v3 = a4.w + bhi.x;
        float bm = fmaxf(fmaxf(v0, v1), fmaxf(v2, v3));
        float bs = __expf(v0 - bm) + __expf(v1 - bm) +
                   __expf(v2 - bm) + __expf(v3 - bm);
        lse_merge(m, s, bm, bs);
        blo = bhi;
      }
    }
    P[ci][cj] = (m < -1e29f) ? NEGF : m + __logf(s);
  }
  __syncthreads();

  // chain: wave 0, private LDS
  if (tid < 64) {
    const int cidx = tid >> 2, g = tid & 3;
    const int s0 = (d == 0) ? TT : 0;
    for (int st = s0; st <= 30; ++st) {
      int ilmin = 15 - st; if (ilmin < 0) ilmin = 0;
      int ilmax = 30 - st; if (ilmax > 15) ilmax = 15;
      bool act = (cidx <= ilmax - ilmin);
      int tci = ilmin + (act ? cidx : 0);
      int tcj = tci + st - 15;
      int c1 = (d == 0) ? (st - 15) : (TT - tci);
      int c2 = (d == 0) ? 0 : tcj;
      int nt = c1 + c2;
      float m  = (g == 0) ? P[tci][tcj] : NEGF;
      float sa = (g == 0) ? 1.f : 0.f;
      float tv[8];
      #pragma unroll
      for (int u = 0; u < 8; ++u) {
        int t = g + 4 * u;
        bool ok = act && (t < nt);
        int tc = ok ? t : 0;
        float va, vb;
        if (tc < c1) {
          int kk = tci + tc;                 // local col in tile (I,*)
          va = (d == 0) ? T[tci][kk] : A[tci][kk];
          int r2 = kk + 1;
          if (r2 <= 15) vb = T[r2][tcj];
          else          vb = (d == 1) ? Bt[0][tcj] : brow[tcj];
        } else {
          int tp = tc - c1;                  // local col in tile-col J
          va = T[tci][tp];
          vb = Bt[tp + 1][tcj];
        }
        tv[u] = ok ? (va + vb) : NEGF;
      }
      float m0 = fmaxf(tv[0], tv[1]), m1 = fmaxf(tv[2], tv[3]);
      float m2 = fmaxf(tv[4], tv[5]), m3 = fmaxf(tv[6], tv[7]);
      float bm = fmaxf(fmaxf(m0, m1), fmaxf(m2, m3));
      float bs = (__expf(tv[0] - bm) + __expf(tv[1] - bm)) +
                 (__expf(tv[2] - bm) + __expf(tv[3] - bm)) +
                 (__expf(tv[4] - bm) + __expf(tv[5] - bm)) +
                 (__expf(tv[6] - bm) + __expf(tv[7] - bm));
      lse_merge(m, sa, bm, bs);
      lse_merge(m, sa, dppf<0xB1>(m), dppf<0xB1>(sa));
      lse_merge(m, sa, dppf<0x4E>(m), dppf<0x4E>(sa));
      if (act && g == 0)
        T[tci][tcj] = SP[tci][tcj] + m + __logf(sa);
      __builtin_amdgcn_wave_barrier();
    }
  }
  __syncthreads();
  chG [gi * SS + gj] = T[ci][cj];
  chTG[gj * SS + gi] = T[ci][cj];
}

// ---------------- OUTSIDE, one tile-diagonal ----------------
__global__ __launch_bounds__(256) void outside_diag(const float* __restrict__ rules,
                                                    const int* __restrict__ lens,
                                                    const float* __restrict__ chG_,
                                                    const float* __restrict__ chTG_,
                                                    float* __restrict__ odG_,
                                                    float* __restrict__ odTG_,
                                                    int d) {
  const int ntiles = NTL - d;
  const int b = blockIdx.x / ntiles;
  const int I = blockIdx.x % ntiles;
  const int J = I + d;
  const int L = lens[b];
  if (TT * J >= L) return;                      // inactive tile: odG stays NEG
  const int tid = threadIdx.x;
  const int ci = tid >> 4, cj = tid & 15;
  const int gi = TT * I + ci, gj = TT * J + cj;
  const float* __restrict__ R = rules + (size_t)b * SS * SS;
  const float* __restrict__ chG  = chG_  + (size_t)b * SS * SS;
  const float* __restrict__ chTG = chTG_ + (size_t)b * SS * SS;
  float* __restrict__ odG  = odG_  + (size_t)b * SS * SS;
  float* __restrict__ odTG = odTG_ + (size_t)b * SS * SS;

  __shared__ float A[TT][TT + 1], Bt[TT][TT + 1], T[TT][TT + 1];
  __shared__ float P[TT][TT + 1], SP[TT][TT + 1];

  const float spv_own = softplusf(R[gi * SS + gj]);
  SP[ci][cj] = spv_own;
  A[ci][cj]  = chG[(TT * I + ci) * SS + TT * I + cj];
  Bt[ci][cj] = chG[(TT * J + ci) * SS + TT * J + cj];
  const bool isroot = (gi == 0) && (gj == L - 1);
  T[ci][cj] = isroot ? spv_own : NEGF;          // root: od = 0 + sp

  // interior partial: left parents p>=16(J+1) (odG rows NEG beyond L),
  // right parents a<16I
  {
    float m = NEGF, s = 0.f;
    const float* odRow    = odG + gi * SS;
    const float* chRowJ1  = chG + (gj + 1) * SS;     // used only if loop runs
    const int p0 = TT * (J + 1);
    for (int p = p0; p < SS; p += 4) {
      float4 o4 = *reinterpret_cast<const float4*>(odRow + p);
      float4 c4 = *reinterpret_cast<const float4*>(chRowJ1 + p);
      float v0 = o4.x + c4.x, v1 = o4.y + c4.y;
      float v2 = o4.z + c4.z, v3 = o4.w + c4.w;
      float bm = fmaxf(fmaxf(v0, v1), fmaxf(v2, v3));
      float bs = __expf(v0 - bm) + __expf(v1 - bm) +
                 __expf(v2 - bm) + __expf(v3 - bm);
      lse_merge(m, s, bm, bs);
    }
    const float* odTRow   = odTG + gj * SS;
    const float* chTRowI1 = chTG + (gi - 1) * SS;    // used only if loop runs
    const int aEnd = TT * I;
    for (int a = 0; a < aEnd; a += 4) {
      float4 o4 = *reinterpret_cast<const float4*>(odTRow + a);
      float4 c4 = *reinterpret_cast<const float4*>(chTRowI1 + a);
      float v0 = o4.x + c4.x, v1 = o4.y + c4.y;
      float v2 = o4.z + c4.z, v3 = o4.w + c4.w;
      float bm = fmaxf(fmaxf(v0, v1), fmaxf(v2, v3));
      float bs = __expf(v0 - bm) + __expf(v1 - bm) +
                 __expf(v2 - bm) + __expf(v3 - bm);
      lse_merge(m, s, bm, bs);
    }
    P[ci][cj] = (m < -1e29f) ? NEGF : m + __logf(s);
  }
  __syncthreads();

  // chain: wave 0, sub-diagonals DESCENDING
  if (tid < 64) {
    const int cidx = tid >> 2, g = tid & 3;
    const int sEnd = (d == 0) ? 15 : 0;
    for (int st = 30; st >= sEnd; --st) {
      int ilmin = 15 - st; if (ilmin < 0) ilmin = 0;
      int ilmax = 30 - st; if (ilmax > 15) ilmax = 15;
      bool act = (cidx <= ilmax - ilmin);
      int tci = ilmin + (act ? cidx : 0);
      int tcj = tci + st - 15;
      int tgi = TT * I + tci, tgj = TT * J + tcj;
      bool rooted = (tgi == 0 && tgj == L - 1);
      bool dowrite = act && (tgj < L) && !rooted;
      int c1 = 15 - tcj, c2 = tci;
      int nt = c1 + c2;
      float m  = (g == 0) ? P[tci][tcj] : NEGF;
      float sa = (g == 0) ? 1.f : 0.f;
      int cim1 = (tci > 0) ? tci - 1 : 0;            // clamp (masked lanes only)
      float tv[8];
      #pragma unroll
      for (int u = 0; u < 8; ++u) {
        int t = g + 4 * u;
        bool ok = act && (t < nt);
        int tc = ok ? t : 0;
        float va, vb;
        if (tc < c1) {
          int pl = tcj + 1 + tc;                     // col in tile-col J
          va = T[tci][pl];
          vb = Bt[tcj + 1][pl];
        } else {
          int al = tc - c1;                          // row in tile-row I
          va = T[al][tcj];
          vb = A[al][cim1];
        }
        tv[u] = ok ? (va + vb) : NEGF;
      }
      float m0 = fmaxf(tv[0], tv[1]), m1 = fmaxf(tv[2], tv[3]);
      float m2 = fmaxf(tv[4], tv[5]), m3 = fmaxf(tv[6], tv[7]);
      float bm = fmaxf(fmaxf(m0, m1), fmaxf(m2, m3));
      float bs = (__expf(tv[0] - bm) + __expf(tv[1] - bm)) +
                 (__expf(tv[2] - bm) + __expf(tv[3] - bm)) +
                 (__expf(tv[4] - bm) + __expf(tv[5] - bm)) +
                 (__expf(tv[6] - bm) + __expf(tv[7] - bm));
      lse_merge(m, sa, bm, bs);
      lse_merge(m, sa, dppf<0xB1>(m), dppf<0xB1>(sa));
      lse_merge(m, sa, dppf<0x4E>(m), dppf<0x4E>(sa));
      if (dowrite && g == 0)
        T[tci][tcj] = SP[tci][tcj] + m + __logf(sa);
      __builtin_amdgcn_wave_barrier();
    }
  }
  __syncthreads();
  odG [gi * SS + gj] = T[ci][cj];
  odTG[gj * SS + gi] = T[ci][cj];
}

// ---------------- MARGINALS + Z ----------------
__global__ __launch_bounds__(256) void cky_marg(const float* __restrict__ rules,
                                                const int* __restrict__ lens,
                                                const float* __restrict__ chG_,
                                                const float* __restrict__ odG_,
                                                float* __restrict__ outZ,
                                                float* __restrict__ marg) {
  const int total = BB * SS * SS;
  for (int idx = blockIdx.x * 256 + threadIdx.x; idx < total; idx += gridDim.x * 256) {
    int b = idx / (SS * SS);
    int rem = idx - b * SS * SS;
    int i = rem / SS, j = rem - i * SS;
    int L = lens[b];
    if (rem == 0) outZ[b] = chG_[(size_t)b * SS * SS + (L - 1)];
    float val = 0.f;
    if (i <= j && j < L) {
      float r = rules[idx];
      float sp = softplusf(r);
      float Z = chG_[(size_t)b * SS * SS + (L - 1)];
      float o = odG_[idx] - sp;
      float c = chG_[idx];
      float sig = 1.f / (1.f + __expf(-r));
      val = sig * __expf(o + c - Z);
    }
    marg[idx] = val;
  }
}

extern "C" void kernel_launch(void* const* d_in, const int* in_sizes, int n_in,
                              void* d_out, int out_size, void* d_ws, size_t ws_size,
                              hipStream_t stream) {
  const float* rules = (const float*)d_in[0];   // (B,S,S,1) f32
  const int* lens = (const int*)d_in[1];        // (B,) i32
  float* outZ = (float*)d_out;                  // [0:16) = Z
  float* marg = (float*)d_out + BB;             // [16:) = marginal

  float* chG_  = (float*)d_ws;                          // B*S*S
  float* chTG_ = chG_  + (size_t)BB * SS * SS;          // B*S*S
  float* odG_  = chTG_ + (size_t)BB * SS * SS;          // B*S*S
  float* odTG_ = odG_  + (size_t)BB * SS * SS;          // B*S*S

  init_od<<<256, 256, 0, stream>>>(odG_, odTG_);
  for (int d = 0; d < NTL; ++d)
    inside_diag<<<BB * (NTL - d), 256, 0, stream>>>(rules, chG_, chTG_, d);
  for (int d = NTL - 1; d >= 0; --d)
    outside_diag<<<BB * (NTL - d), 256, 0, stream>>>(rules, lens, chG_, chTG_,
                                                     odG_, odTG_, d);
  cky_marg<<<(BB * SS * SS + 255) / 256, 256, 0, stream>>>(rules, lens, chG_,
                                                           odG_, outZ, marg);
}